// Round 2
// baseline (785.001 us; speedup 1.0000x reference)
//
#include <hip/hip_runtime.h>
#include <hip/hip_bf16.h>

// TokenRoutedMLP: N=32768 tokens, H=1024, 8 routed experts (id%8) + shared expert.
// Strategy: grouped bf16 MFMA GEMMs with shared expert folded in via concat weights.
//   inter[m, 0:512]  = silu(x@gate_e)*(x@up_e)        (routed)
//   inter[m, 512:1024] = silu(x@sgW^T)*(x@suW^T)      (shared)
//   out[tok] = inter @ [down_e ; sdW^T]               (K=1024)
// NOTE: harness passes ALL integer inputs as int32 (token_ids int64 -> int32).

#define N_TOK 32768
#define HD 1024
#define NE 8

typedef __attribute__((ext_vector_type(8))) short bf16x8;
typedef __attribute__((ext_vector_type(8))) unsigned short u16x8;
typedef __attribute__((ext_vector_type(4))) float f32x4;

__device__ __forceinline__ unsigned short f2bf(float f) {
  unsigned int x = __float_as_uint(f);
  x += 0x7fffu + ((x >> 16) & 1u);   // RTNE
  return (unsigned short)(x >> 16);
}

__device__ __forceinline__ void gld16(const unsigned short* g, unsigned short* l) {
  __builtin_amdgcn_global_load_lds(
      (const __attribute__((address_space(1))) unsigned int*)g,
      (__attribute__((address_space(3))) unsigned int*)l,
      16, 0, 0);
}

__device__ __forceinline__ int expert_of(int id) {
  int v = id < 0 ? 0 : (id > 99999 ? 99999 : id);
  return v & 7;
}

// ---------------- routing ----------------
__global__ void k_zero(int* ctrl) {
  if (threadIdx.x < 16) ctrl[threadIdx.x] = 0;   // cnt[8], cursor[8]
}

__global__ void k_count(const int* __restrict__ ids, int* __restrict__ cnt) {
  int t = blockIdx.x * 256 + threadIdx.x;
  if (t >= N_TOK) return;
  atomicAdd(&cnt[expert_of(ids[t])], 1);
}

__global__ void k_scan(const int* __restrict__ cnt, int* __restrict__ off) {
  if (threadIdx.x == 0 && blockIdx.x == 0) {
    int a = 0;
    for (int e = 0; e < NE; e++) { off[e] = a; a += (cnt[e] + 127) & ~127; }
    off[NE] = a;
  }
}

__global__ void k_fill(const int* __restrict__ ids, int* __restrict__ cursor,
                       const int* __restrict__ off, int* __restrict__ perm) {
  int t = blockIdx.x * 256 + threadIdx.x;
  if (t >= N_TOK) return;
  int e = expert_of(ids[t]);
  int pos = off[e] + atomicAdd(&cursor[e], 1);
  perm[pos] = t;
}

// ---------------- conversions / weight build ----------------
__global__ void k_cvt_x(const float* __restrict__ src, unsigned short* __restrict__ dst) {
  size_t i = ((size_t)blockIdx.x * 256 + threadIdx.x) * 8;
  float4 a = *reinterpret_cast<const float4*>(src + i);
  float4 b = *reinterpret_cast<const float4*>(src + i + 4);
  u16x8 o;
  o[0]=f2bf(a.x); o[1]=f2bf(a.y); o[2]=f2bf(a.z); o[3]=f2bf(a.w);
  o[4]=f2bf(b.x); o[5]=f2bf(b.y); o[6]=f2bf(b.z); o[7]=f2bf(b.w);
  *reinterpret_cast<u16x8*>(dst + i) = o;
}

// transpose-convert: src f32 [R][C] (per expert) -> dst bf16 rows=C, dst[c][r]
__global__ void k_transpose_cvt(const float* __restrict__ src0, unsigned short* __restrict__ dst0,
                                int R, int C, int dst_stride,
                                size_t src_estride, size_t dst_estride) {
  const float* src = src0 + blockIdx.z * src_estride;
  unsigned short* dst = dst0 + blockIdx.z * dst_estride;
  __shared__ __attribute__((aligned(16))) float tile[32][33];
  int t = threadIdx.x;
  int r0 = blockIdx.y * 32, c0 = blockIdx.x * 32;
  int row = t >> 3, c4 = (t & 7) * 4;
  float4 v = *reinterpret_cast<const float4*>(src + (size_t)(r0 + row) * C + c0 + c4);
  tile[row][c4+0] = v.x; tile[row][c4+1] = v.y; tile[row][c4+2] = v.z; tile[row][c4+3] = v.w;
  __syncthreads();
  ushort4 o;
  o.x = f2bf(tile[c4+0][row]); o.y = f2bf(tile[c4+1][row]);
  o.z = f2bf(tile[c4+2][row]); o.w = f2bf(tile[c4+3][row]);
  *reinterpret_cast<ushort4*>(dst + (size_t)(c0 + row) * dst_stride + r0 + c4) = o;
}

// copy-convert: src f32 [rows][cols] -> dst bf16 at [drow+r][dcol+c], replicated per z
__global__ void k_copy_cvt(const float* __restrict__ src, unsigned short* __restrict__ dst,
                           int rows, int cols, int dst_stride, int drow, int dcol,
                           size_t dst_estride) {
  size_t i = ((size_t)blockIdx.x * 256 + threadIdx.x) * 4;
  if (i >= (size_t)rows * cols) return;
  int r = (int)(i / cols), c = (int)(i % cols);
  float4 v = *reinterpret_cast<const float4*>(src + i);
  ushort4 o; o.x=f2bf(v.x); o.y=f2bf(v.y); o.z=f2bf(v.z); o.w=f2bf(v.w);
  *reinterpret_cast<ushort4*>(dst + blockIdx.z * dst_estride
                              + (size_t)(drow + r) * dst_stride + dcol + c) = o;
}

// ---------------- GEMM 1: gate/up + silu*mul -> inter (bf16) ----------------
// block 256 thr = 4 waves (2x2). tile: M=128, N=64 (of gate) + same 64 cols of up. BK=32.
__global__ __launch_bounds__(256) void k_gu(
    const unsigned short* __restrict__ xbf,
    const unsigned short* __restrict__ Gt,   // [8][1024][1024] B^T
    const unsigned short* __restrict__ Ut,
    const int* __restrict__ perm, const int* __restrict__ cnt, const int* __restrict__ off,
    unsigned short* __restrict__ inter) {
  const int e = blockIdx.z;
  const int ce = cnt[e];
  const int m0 = blockIdx.y * 128;
  if (m0 >= ce) return;
  const int n0 = blockIdx.x * 64;
  const int oe = off[e];
  __shared__ __attribute__((aligned(16))) unsigned short smA[128 * 32];
  __shared__ __attribute__((aligned(16))) unsigned short smG[64 * 32];
  __shared__ __attribute__((aligned(16))) unsigned short smU[64 * 32];
  const int tid = threadIdx.x;
  const int lane = tid & 63, wv = tid >> 6;
  const int wr = wv >> 1, wc = wv & 1;
  const int rr = wv * 16 + (lane >> 2);
  const int kb = (lane & 3) * 8;
  int i0 = m0 + rr;        if (i0 > ce - 1) i0 = ce - 1;
  int i1 = m0 + 64 + rr;   if (i1 > ce - 1) i1 = ce - 1;
  const int t0 = perm[oe + i0];
  const int t1 = perm[oe + i1];
  const unsigned short* sA0 = xbf + (size_t)t0 * HD + kb;
  const unsigned short* sA1 = xbf + (size_t)t1 * HD + kb;
  const unsigned short* sG = Gt + ((size_t)e << 20) + (size_t)(n0 + rr) * HD + kb;
  const unsigned short* sU = Ut + ((size_t)e << 20) + (size_t)(n0 + rr) * HD + kb;
  unsigned short* lA0 = smA + wv * 512;
  unsigned short* lA1 = smA + 2048 + wv * 512;
  unsigned short* lG = smG + wv * 512;
  unsigned short* lU = smU + wv * 512;

  f32x4 ag[4][2], au[4][2];
#pragma unroll
  for (int mi = 0; mi < 4; mi++)
#pragma unroll
    for (int ni = 0; ni < 2; ni++) {
      ag[mi][ni] = (f32x4){0.f, 0.f, 0.f, 0.f};
      au[mi][ni] = (f32x4){0.f, 0.f, 0.f, 0.f};
    }

  for (int k0 = 0; k0 < HD; k0 += 32) {
    __syncthreads();
    gld16(sA0 + k0, lA0);
    gld16(sA1 + k0, lA1);
    gld16(sG + k0, lG);
    gld16(sU + k0, lU);
    __syncthreads();
    bf16x8 a[4], g[2], u[2];
#pragma unroll
    for (int mi = 0; mi < 4; mi++)
      a[mi] = *reinterpret_cast<const bf16x8*>(&smA[(wr * 64 + mi * 16 + (lane & 15)) * 32 + (lane >> 4) * 8]);
#pragma unroll
    for (int ni = 0; ni < 2; ni++) {
      g[ni] = *reinterpret_cast<const bf16x8*>(&smG[(wc * 32 + ni * 16 + (lane & 15)) * 32 + (lane >> 4) * 8]);
      u[ni] = *reinterpret_cast<const bf16x8*>(&smU[(wc * 32 + ni * 16 + (lane & 15)) * 32 + (lane >> 4) * 8]);
    }
#pragma unroll
    for (int mi = 0; mi < 4; mi++)
#pragma unroll
      for (int ni = 0; ni < 2; ni++) {
        ag[mi][ni] = __builtin_amdgcn_mfma_f32_16x16x32_bf16(a[mi], g[ni], ag[mi][ni], 0, 0, 0);
        au[mi][ni] = __builtin_amdgcn_mfma_f32_16x16x32_bf16(a[mi], u[ni], au[mi][ni], 0, 0, 0);
      }
  }
  // epilogue: silu(gate)*up -> bf16 inter (unguarded: padding rows have real storage)
#pragma unroll
  for (int mi = 0; mi < 4; mi++)
#pragma unroll
    for (int ni = 0; ni < 2; ni++)
#pragma unroll
      for (int r = 0; r < 4; r++) {
        int m = wr * 64 + mi * 16 + (lane >> 4) * 4 + r;
        int col = n0 + wc * 32 + ni * 16 + (lane & 15);
        float gv = ag[mi][ni][r];
        float uv = au[mi][ni][r];
        float sv = (gv / (1.f + __expf(-gv))) * uv;
        inter[(size_t)(oe + m0 + m) * HD + col] = f2bf(sv);
      }
}

// ---------------- GEMM 2: inter @ Dcat -> out (scatter rows via perm) ----------------
__global__ __launch_bounds__(256) void k_down(
    const unsigned short* __restrict__ inter,
    const unsigned short* __restrict__ Dt,   // [8][1024][1024] B^T
    const int* __restrict__ perm, const int* __restrict__ cnt, const int* __restrict__ off,
    float* __restrict__ out) {
  const int e = blockIdx.z;
  const int ce = cnt[e];
  const int m0 = blockIdx.y * 128;
  if (m0 >= ce) return;
  const int n0 = blockIdx.x * 128;
  const int oe = off[e];
  __shared__ __attribute__((aligned(16))) unsigned short smA[128 * 32];
  __shared__ __attribute__((aligned(16))) unsigned short smB[128 * 32];
  const int tid = threadIdx.x;
  const int lane = tid & 63, wv = tid >> 6;
  const int wr = wv >> 1, wc = wv & 1;
  const int rr = wv * 16 + (lane >> 2);
  const int kb = (lane & 3) * 8;
  const unsigned short* sA0 = inter + (size_t)(oe + m0 + rr) * HD + kb;
  const unsigned short* sA1 = inter + (size_t)(oe + m0 + 64 + rr) * HD + kb;
  const unsigned short* sB0 = Dt + ((size_t)e << 20) + (size_t)(n0 + rr) * HD + kb;
  const unsigned short* sB1 = Dt + ((size_t)e << 20) + (size_t)(n0 + 64 + rr) * HD + kb;
  unsigned short* lA0 = smA + wv * 512;
  unsigned short* lA1 = smA + 2048 + wv * 512;
  unsigned short* lB0 = smB + wv * 512;
  unsigned short* lB1 = smB + 2048 + wv * 512;

  f32x4 acc[4][4];
#pragma unroll
  for (int mi = 0; mi < 4; mi++)
#pragma unroll
    for (int ni = 0; ni < 4; ni++) acc[mi][ni] = (f32x4){0.f, 0.f, 0.f, 0.f};

  for (int k0 = 0; k0 < HD; k0 += 32) {
    __syncthreads();
    gld16(sA0 + k0, lA0);
    gld16(sA1 + k0, lA1);
    gld16(sB0 + k0, lB0);
    gld16(sB1 + k0, lB1);
    __syncthreads();
    bf16x8 a[4], b[4];
#pragma unroll
    for (int i = 0; i < 4; i++) {
      a[i] = *reinterpret_cast<const bf16x8*>(&smA[(wr * 64 + i * 16 + (lane & 15)) * 32 + (lane >> 4) * 8]);
      b[i] = *reinterpret_cast<const bf16x8*>(&smB[(wc * 64 + i * 16 + (lane & 15)) * 32 + (lane >> 4) * 8]);
    }
#pragma unroll
    for (int mi = 0; mi < 4; mi++)
#pragma unroll
      for (int ni = 0; ni < 4; ni++)
        acc[mi][ni] = __builtin_amdgcn_mfma_f32_16x16x32_bf16(a[mi], b[ni], acc[mi][ni], 0, 0, 0);
  }
#pragma unroll
  for (int mi = 0; mi < 4; mi++)
#pragma unroll
    for (int ni = 0; ni < 4; ni++)
#pragma unroll
      for (int r = 0; r < 4; r++) {
        int m = wr * 64 + mi * 16 + (lane >> 4) * 4 + r;
        int gm = m0 + m;
        if (gm < ce) {
          int t = perm[oe + gm];
          out[(size_t)t * HD + n0 + wc * 64 + ni * 16 + (lane & 15)] = acc[mi][ni][r];
        }
      }
}

// ---------------- naive fp32 fallback (only if ws too small) ----------------
__global__ __launch_bounds__(256) void k_naive(
    const float* __restrict__ x, const int* __restrict__ ids,
    const float* __restrict__ gw, const float* __restrict__ uw, const float* __restrict__ dw,
    const float* __restrict__ sgw, const float* __restrict__ suw, const float* __restrict__ sdw,
    float* __restrict__ out) {
  const int t = blockIdx.x;
  const int tid = threadIdx.x;
  __shared__ float sx[1024];
  __shared__ float si[1024];
  for (int i = tid; i < 1024; i += 256) sx[i] = x[(size_t)t * 1024 + i];
  const int e = expert_of(ids[t]);
  __syncthreads();
  const float* gwe = gw + (size_t)e * 1024 * 512;
  const float* uwe = uw + (size_t)e * 1024 * 512;
  for (int j = tid; j < 512; j += 256) {
    float g = 0, u = 0, sg = 0, su = 0;
    for (int k = 0; k < 1024; k++) {
      float xv = sx[k];
      g += xv * gwe[(size_t)k * 512 + j];
      u += xv * uwe[(size_t)k * 512 + j];
      sg += xv * sgw[(size_t)j * 1024 + k];
      su += xv * suw[(size_t)j * 1024 + k];
    }
    si[j] = g / (1.f + __expf(-g)) * u;
    si[512 + j] = sg / (1.f + __expf(-sg)) * su;
  }
  __syncthreads();
  const float* dwe = dw + (size_t)e * 512 * 1024;
  for (int n = tid; n < 1024; n += 256) {
    float a = 0;
    for (int k = 0; k < 512; k++)
      a += si[k] * dwe[(size_t)k * 1024 + n] + si[512 + k] * sdw[(size_t)n * 512 + k];
    out[(size_t)t * 1024 + n] = a;
  }
}

extern "C" void kernel_launch(void* const* d_in, const int* in_sizes, int n_in,
                              void* d_out, int out_size, void* d_ws, size_t ws_size,
                              hipStream_t stream) {
  const float* x = (const float*)d_in[0];
  const int* ids = (const int*)d_in[1];          // harness passes integers as int32
  const float* gw = (const float*)d_in[2];
  const float* uw = (const float*)d_in[3];
  const float* dw = (const float*)d_in[4];
  const float* sgw = (const float*)d_in[5];
  const float* suw = (const float*)d_in[6];
  const float* sdw = (const float*)d_in[7];
  float* out = (float*)d_out;

  const size_t REQ = 186908672ull;
  if (ws_size < REQ) {
    k_naive<<<N_TOK, 256, 0, stream>>>(x, ids, gw, uw, dw, sgw, suw, sdw, out);
    return;
  }

  char* ws = (char*)d_ws;
  int* ctrl = (int*)ws;                                   // cnt[8] | cursor[8] | off[9]
  int* perm = (int*)(ws + 1024);                          // 33792 ints
  unsigned short* xbf = (unsigned short*)(ws + 262144);   // [32768][1024]
  unsigned short* Gt = (unsigned short*)(ws + 67371008ull);   // [8][1024][1024]
  unsigned short* Ut = (unsigned short*)(ws + 84148224ull);
  unsigned short* Dt = (unsigned short*)(ws + 100925440ull);
  unsigned short* inter = (unsigned short*)(ws + 117702656ull); // [33792][1024]

  k_zero<<<1, 64, 0, stream>>>(ctrl);
  k_count<<<128, 256, 0, stream>>>(ids, ctrl);
  k_scan<<<1, 64, 0, stream>>>(ctrl, ctrl + 16);
  k_fill<<<128, 256, 0, stream>>>(ids, ctrl + 8, ctrl + 16, perm);
  k_cvt_x<<<16384, 256, 0, stream>>>(x, xbf);
  // routed transposes: gate/up [1024][512] -> [512][1024]; down [512][1024] -> [1024][512]
  k_transpose_cvt<<<dim3(16, 32, 8), 256, 0, stream>>>(gw, Gt, 1024, 512, 1024,
                                                       (size_t)1024 * 512, (size_t)1 << 20);
  k_transpose_cvt<<<dim3(16, 32, 8), 256, 0, stream>>>(uw, Ut, 1024, 512, 1024,
                                                       (size_t)1024 * 512, (size_t)1 << 20);
  k_transpose_cvt<<<dim3(32, 16, 8), 256, 0, stream>>>(dw, Dt, 512, 1024, 1024,
                                                       (size_t)512 * 1024, (size_t)1 << 20);
  // shared weights appended (replicated per expert)
  k_copy_cvt<<<dim3(512, 1, 8), 256, 0, stream>>>(sgw, Gt, 512, 1024, 1024, 512, 0, (size_t)1 << 20);
  k_copy_cvt<<<dim3(512, 1, 8), 256, 0, stream>>>(suw, Ut, 512, 1024, 1024, 512, 0, (size_t)1 << 20);
  k_copy_cvt<<<dim3(512, 1, 8), 256, 0, stream>>>(sdw, Dt, 1024, 512, 1024, 0, 512, (size_t)1 << 20);
  // grouped GEMMs
  k_gu<<<dim3(16, 256, 8), 256, 0, stream>>>(xbf, Gt, Ut, perm, ctrl, ctrl + 16, inter);
  k_down<<<dim3(8, 256, 8), 256, 0, stream>>>(inter, Dt, perm, ctrl, ctrl + 16, out);
}

// Round 3
// 647.891 us; speedup vs baseline: 1.2116x; 1.2116x over previous
//
#include <hip/hip_runtime.h>
#include <hip/hip_bf16.h>

// TokenRoutedMLP: N=32768 tokens, H=1024, 8 routed experts (id%8) + shared expert.
// Grouped bf16 MFMA GEMMs; shared expert folded in via concat weights.
//   inter[m, 0:512]   = silu(x@gate_e)*(x@up_e)     (routed)
//   inter[m, 512:1024]= silu(x@sgW^T)*(x@suW^T)     (shared)
//   out[tok] = inter @ [down_e ; sdW^T]             (K=1024)
// NOTE: harness passes ALL integer inputs as int32 (token_ids int64 -> int32).

#define N_TOK 32768
#define HD 1024
#define NE 8

typedef __attribute__((ext_vector_type(8))) short bf16x8;
typedef __attribute__((ext_vector_type(8))) unsigned short u16x8;
typedef __attribute__((ext_vector_type(4))) float f32x4;

__device__ __forceinline__ unsigned short f2bf(float f) {
  unsigned int x = __float_as_uint(f);
  x += 0x7fffu + ((x >> 16) & 1u);   // RTNE
  return (unsigned short)(x >> 16);
}

__device__ __forceinline__ void gld16(const unsigned short* g, unsigned short* l) {
  __builtin_amdgcn_global_load_lds(
      (const __attribute__((address_space(1))) unsigned int*)g,
      (__attribute__((address_space(3))) unsigned int*)l,
      16, 0, 0);
}

__device__ __forceinline__ int expert_of(int id) {
  int v = id < 0 ? 0 : (id > 99999 ? 99999 : id);
  return v & 7;
}

// ---------------- routing (LDS-histogram to avoid same-address atomic storms) ----
__global__ void k_zero(int* ctrl) {
  if (threadIdx.x < 16) ctrl[threadIdx.x] = 0;   // cnt[8], cursor[8]
}

__global__ void k_count(const int* __restrict__ ids, int* __restrict__ cnt) {
  __shared__ int l[NE];
  if (threadIdx.x < NE) l[threadIdx.x] = 0;
  __syncthreads();
  int t = blockIdx.x * 256 + threadIdx.x;
  atomicAdd(&l[expert_of(ids[t])], 1);
  __syncthreads();
  if (threadIdx.x < NE) atomicAdd(&cnt[threadIdx.x], l[threadIdx.x]);
}

__global__ void k_scan(const int* __restrict__ cnt, int* __restrict__ off) {
  if (threadIdx.x == 0 && blockIdx.x == 0) {
    int a = 0;
    for (int e = 0; e < NE; e++) { off[e] = a; a += (cnt[e] + 127) & ~127; }
    off[NE] = a;
  }
}

__global__ void k_fill(const int* __restrict__ ids, int* __restrict__ cursor,
                       const int* __restrict__ off, int* __restrict__ perm) {
  __shared__ int lcnt[NE], lbase[NE];
  if (threadIdx.x < NE) lcnt[threadIdx.x] = 0;
  __syncthreads();
  int t = blockIdx.x * 256 + threadIdx.x;
  int e = expert_of(ids[t]);
  int r = atomicAdd(&lcnt[e], 1);          // rank within block
  __syncthreads();
  if (threadIdx.x < NE)
    lbase[threadIdx.x] = atomicAdd(&cursor[threadIdx.x], lcnt[threadIdx.x]);
  __syncthreads();
  perm[off[e] + lbase[e] + r] = t;
}

// ---------------- conversions / weight build ----------------
__global__ void k_cvt_x(const float* __restrict__ src, unsigned short* __restrict__ dst) {
  size_t i = ((size_t)blockIdx.x * 256 + threadIdx.x) * 8;
  float4 a = *reinterpret_cast<const float4*>(src + i);
  float4 b = *reinterpret_cast<const float4*>(src + i + 4);
  u16x8 o;
  o[0]=f2bf(a.x); o[1]=f2bf(a.y); o[2]=f2bf(a.z); o[3]=f2bf(a.w);
  o[4]=f2bf(b.x); o[5]=f2bf(b.y); o[6]=f2bf(b.z); o[7]=f2bf(b.w);
  *reinterpret_cast<u16x8*>(dst + i) = o;
}

// transpose-convert: src f32 [R][C] (per expert) -> dst bf16 rows=C, dst[c][r]
__global__ void k_transpose_cvt(const float* __restrict__ src0, unsigned short* __restrict__ dst0,
                                int R, int C, int dst_stride,
                                size_t src_estride, size_t dst_estride) {
  const float* src = src0 + blockIdx.z * src_estride;
  unsigned short* dst = dst0 + blockIdx.z * dst_estride;
  __shared__ __attribute__((aligned(16))) float tile[32][33];
  int t = threadIdx.x;
  int r0 = blockIdx.y * 32, c0 = blockIdx.x * 32;
  int row = t >> 3, c4 = (t & 7) * 4;
  float4 v = *reinterpret_cast<const float4*>(src + (size_t)(r0 + row) * C + c0 + c4);
  tile[row][c4+0] = v.x; tile[row][c4+1] = v.y; tile[row][c4+2] = v.z; tile[row][c4+3] = v.w;
  __syncthreads();
  ushort4 o;
  o.x = f2bf(tile[c4+0][row]); o.y = f2bf(tile[c4+1][row]);
  o.z = f2bf(tile[c4+2][row]); o.w = f2bf(tile[c4+3][row]);
  *reinterpret_cast<ushort4*>(dst + (size_t)(c0 + row) * dst_stride + r0 + c4) = o;
}

// copy-convert: src f32 [rows][cols] -> dst bf16 at [drow+r][dcol+c], replicated per z
__global__ void k_copy_cvt(const float* __restrict__ src, unsigned short* __restrict__ dst,
                           int rows, int cols, int dst_stride, int drow, int dcol,
                           size_t dst_estride) {
  size_t i = ((size_t)blockIdx.x * 256 + threadIdx.x) * 4;
  if (i >= (size_t)rows * cols) return;
  int r = (int)(i / cols), c = (int)(i % cols);
  float4 v = *reinterpret_cast<const float4*>(src + i);
  ushort4 o; o.x=f2bf(v.x); o.y=f2bf(v.y); o.z=f2bf(v.z); o.w=f2bf(v.w);
  *reinterpret_cast<ushort4*>(dst + blockIdx.z * dst_estride
                              + (size_t)(drow + r) * dst_stride + dcol + c) = o;
}

// ---------------- GEMM 1: gate/up + silu*mul -> inter (bf16) ----------------
// block 256 thr = 4 waves (2x2). tile: M=128, N=128 (of gate AND up). BK=32.
// per wave-K-step: 32 MFMA, 12 ds_read_b128, 6 global_load_lds.
__global__ __launch_bounds__(256) void k_gu(
    const unsigned short* __restrict__ xbf,
    const unsigned short* __restrict__ Gt,   // [8][1024][1024] B^T (rows = out cols)
    const unsigned short* __restrict__ Ut,
    const int* __restrict__ perm, const int* __restrict__ cnt, const int* __restrict__ off,
    unsigned short* __restrict__ inter) {
  const int e = blockIdx.z;
  const int ce = cnt[e];
  const int m0 = blockIdx.y * 128;
  if (m0 >= ce) return;
  const int n0 = blockIdx.x * 128;
  const int oe = off[e];
  __shared__ __attribute__((aligned(16))) unsigned short smA[128 * 32];
  __shared__ __attribute__((aligned(16))) unsigned short smG[128 * 32];
  __shared__ __attribute__((aligned(16))) unsigned short smU[128 * 32];
  const int tid = threadIdx.x;
  const int lane = tid & 63, wv = tid >> 6;
  const int wr = wv >> 1, wc = wv & 1;
  const int rr = wv * 16 + (lane >> 2);
  const int kb = (lane & 3) * 8;
  int i0 = m0 + rr;        if (i0 > ce - 1) i0 = ce - 1;
  int i1 = m0 + 64 + rr;   if (i1 > ce - 1) i1 = ce - 1;
  const int t0 = perm[oe + i0];
  const int t1 = perm[oe + i1];
  const unsigned short* sA0 = xbf + (size_t)t0 * HD + kb;
  const unsigned short* sA1 = xbf + (size_t)t1 * HD + kb;
  const unsigned short* sG0 = Gt + ((size_t)e << 20) + (size_t)(n0 + rr) * HD + kb;
  const unsigned short* sG1 = sG0 + (size_t)64 * HD;
  const unsigned short* sU0 = Ut + ((size_t)e << 20) + (size_t)(n0 + rr) * HD + kb;
  const unsigned short* sU1 = sU0 + (size_t)64 * HD;
  unsigned short* lA0 = smA + wv * 512;
  unsigned short* lA1 = smA + 2048 + wv * 512;
  unsigned short* lG0 = smG + wv * 512;
  unsigned short* lG1 = smG + 2048 + wv * 512;
  unsigned short* lU0 = smU + wv * 512;
  unsigned short* lU1 = smU + 2048 + wv * 512;

  f32x4 ag[4][4], au[4][4];
#pragma unroll
  for (int mi = 0; mi < 4; mi++)
#pragma unroll
    for (int ni = 0; ni < 4; ni++) {
      ag[mi][ni] = (f32x4){0.f, 0.f, 0.f, 0.f};
      au[mi][ni] = (f32x4){0.f, 0.f, 0.f, 0.f};
    }

  for (int k0 = 0; k0 < HD; k0 += 32) {
    __syncthreads();
    gld16(sA0 + k0, lA0);
    gld16(sA1 + k0, lA1);
    gld16(sG0 + k0, lG0);
    gld16(sG1 + k0, lG1);
    gld16(sU0 + k0, lU0);
    gld16(sU1 + k0, lU1);
    __syncthreads();
    bf16x8 a[4], b[4];
#pragma unroll
    for (int mi = 0; mi < 4; mi++)
      a[mi] = *reinterpret_cast<const bf16x8*>(&smA[(wr * 64 + mi * 16 + (lane & 15)) * 32 + (lane >> 4) * 8]);
#pragma unroll
    for (int ni = 0; ni < 4; ni++)
      b[ni] = *reinterpret_cast<const bf16x8*>(&smG[(wc * 64 + ni * 16 + (lane & 15)) * 32 + (lane >> 4) * 8]);
#pragma unroll
    for (int mi = 0; mi < 4; mi++)
#pragma unroll
      for (int ni = 0; ni < 4; ni++)
        ag[mi][ni] = __builtin_amdgcn_mfma_f32_16x16x32_bf16(a[mi], b[ni], ag[mi][ni], 0, 0, 0);
#pragma unroll
    for (int ni = 0; ni < 4; ni++)
      b[ni] = *reinterpret_cast<const bf16x8*>(&smU[(wc * 64 + ni * 16 + (lane & 15)) * 32 + (lane >> 4) * 8]);
#pragma unroll
    for (int mi = 0; mi < 4; mi++)
#pragma unroll
      for (int ni = 0; ni < 4; ni++)
        au[mi][ni] = __builtin_amdgcn_mfma_f32_16x16x32_bf16(a[mi], b[ni], au[mi][ni], 0, 0, 0);
  }
  // epilogue: silu(gate)*up -> bf16 inter (padding rows have real storage; no guard)
#pragma unroll
  for (int mi = 0; mi < 4; mi++)
#pragma unroll
    for (int ni = 0; ni < 4; ni++)
#pragma unroll
      for (int r = 0; r < 4; r++) {
        int m = wr * 64 + mi * 16 + (lane >> 4) * 4 + r;
        int col = n0 + wc * 64 + ni * 16 + (lane & 15);
        float gv = ag[mi][ni][r];
        float uv = au[mi][ni][r];
        float sv = (gv / (1.f + __expf(-gv))) * uv;
        inter[(size_t)(oe + m0 + m) * HD + col] = f2bf(sv);
      }
}

// ---------------- GEMM 2: inter @ Dcat -> out (scatter rows via perm) ----------------
// tile M=128, N=256; 4 waves (2x2), each 64x128. BK=32.
__global__ __launch_bounds__(256) void k_down(
    const unsigned short* __restrict__ inter,
    const unsigned short* __restrict__ Dt,   // [8][1024][1024] B^T
    const int* __restrict__ perm, const int* __restrict__ cnt, const int* __restrict__ off,
    float* __restrict__ out) {
  const int e = blockIdx.z;
  const int ce = cnt[e];
  const int m0 = blockIdx.y * 128;
  if (m0 >= ce) return;
  const int n0 = blockIdx.x * 256;
  const int oe = off[e];
  __shared__ __attribute__((aligned(16))) unsigned short smA[128 * 32];
  __shared__ __attribute__((aligned(16))) unsigned short smB[256 * 32];
  const int tid = threadIdx.x;
  const int lane = tid & 63, wv = tid >> 6;
  const int wr = wv >> 1, wc = wv & 1;
  const int rr = wv * 16 + (lane >> 2);
  const int kb = (lane & 3) * 8;
  const unsigned short* sA0 = inter + (size_t)(oe + m0 + rr) * HD + kb;
  const unsigned short* sA1 = sA0 + (size_t)64 * HD;
  const unsigned short* sB0 = Dt + ((size_t)e << 20) + (size_t)(n0 + rr) * HD + kb;
  const unsigned short* sB1 = sB0 + (size_t)64 * HD;
  const unsigned short* sB2 = sB0 + (size_t)128 * HD;
  const unsigned short* sB3 = sB0 + (size_t)192 * HD;
  unsigned short* lA0 = smA + wv * 512;
  unsigned short* lA1 = smA + 2048 + wv * 512;
  unsigned short* lB0 = smB + wv * 512;
  unsigned short* lB1 = smB + 2048 + wv * 512;
  unsigned short* lB2 = smB + 4096 + wv * 512;
  unsigned short* lB3 = smB + 6144 + wv * 512;

  f32x4 acc[4][8];
#pragma unroll
  for (int mi = 0; mi < 4; mi++)
#pragma unroll
    for (int ni = 0; ni < 8; ni++) acc[mi][ni] = (f32x4){0.f, 0.f, 0.f, 0.f};

  for (int k0 = 0; k0 < HD; k0 += 32) {
    __syncthreads();
    gld16(sA0 + k0, lA0);
    gld16(sA1 + k0, lA1);
    gld16(sB0 + k0, lB0);
    gld16(sB1 + k0, lB1);
    gld16(sB2 + k0, lB2);
    gld16(sB3 + k0, lB3);
    __syncthreads();
    bf16x8 a[4];
#pragma unroll
    for (int mi = 0; mi < 4; mi++)
      a[mi] = *reinterpret_cast<const bf16x8*>(&smA[(wr * 64 + mi * 16 + (lane & 15)) * 32 + (lane >> 4) * 8]);
#pragma unroll
    for (int ni = 0; ni < 8; ni++) {
      bf16x8 b = *reinterpret_cast<const bf16x8*>(&smB[(wc * 128 + ni * 16 + (lane & 15)) * 32 + (lane >> 4) * 8]);
#pragma unroll
      for (int mi = 0; mi < 4; mi++)
        acc[mi][ni] = __builtin_amdgcn_mfma_f32_16x16x32_bf16(a[mi], b, acc[mi][ni], 0, 0, 0);
    }
  }
#pragma unroll
  for (int mi = 0; mi < 4; mi++)
#pragma unroll
    for (int ni = 0; ni < 8; ni++)
#pragma unroll
      for (int r = 0; r < 4; r++) {
        int m = wr * 64 + mi * 16 + (lane >> 4) * 4 + r;
        int gm = m0 + m;
        if (gm < ce) {
          int t = perm[oe + gm];
          out[(size_t)t * HD + n0 + wc * 128 + ni * 16 + (lane & 15)] = acc[mi][ni][r];
        }
      }
}

// ---------------- naive fp32 fallback (only if ws too small) ----------------
__global__ __launch_bounds__(256) void k_naive(
    const float* __restrict__ x, const int* __restrict__ ids,
    const float* __restrict__ gw, const float* __restrict__ uw, const float* __restrict__ dw,
    const float* __restrict__ sgw, const float* __restrict__ suw, const float* __restrict__ sdw,
    float* __restrict__ out) {
  const int t = blockIdx.x;
  const int tid = threadIdx.x;
  __shared__ float sx[1024];
  __shared__ float si[1024];
  for (int i = tid; i < 1024; i += 256) sx[i] = x[(size_t)t * 1024 + i];
  const int e = expert_of(ids[t]);
  __syncthreads();
  const float* gwe = gw + (size_t)e * 1024 * 512;
  const float* uwe = uw + (size_t)e * 1024 * 512;
  for (int j = tid; j < 512; j += 256) {
    float g = 0, u = 0, sg = 0, su = 0;
    for (int k = 0; k < 1024; k++) {
      float xv = sx[k];
      g += xv * gwe[(size_t)k * 512 + j];
      u += xv * uwe[(size_t)k * 512 + j];
      sg += xv * sgw[(size_t)j * 1024 + k];
      su += xv * suw[(size_t)j * 1024 + k];
    }
    si[j] = g / (1.f + __expf(-g)) * u;
    si[512 + j] = sg / (1.f + __expf(-sg)) * su;
  }
  __syncthreads();
  const float* dwe = dw + (size_t)e * 512 * 1024;
  for (int n = tid; n < 1024; n += 256) {
    float a = 0;
    for (int k = 0; k < 512; k++)
      a += si[k] * dwe[(size_t)k * 1024 + n] + si[512 + k] * sdw[(size_t)n * 512 + k];
    out[(size_t)t * 1024 + n] = a;
  }
}

extern "C" void kernel_launch(void* const* d_in, const int* in_sizes, int n_in,
                              void* d_out, int out_size, void* d_ws, size_t ws_size,
                              hipStream_t stream) {
  const float* x = (const float*)d_in[0];
  const int* ids = (const int*)d_in[1];          // harness passes integers as int32
  const float* gw = (const float*)d_in[2];
  const float* uw = (const float*)d_in[3];
  const float* dw = (const float*)d_in[4];
  const float* sgw = (const float*)d_in[5];
  const float* suw = (const float*)d_in[6];
  const float* sdw = (const float*)d_in[7];
  float* out = (float*)d_out;

  const size_t REQ = 186908672ull;
  if (ws_size < REQ) {
    k_naive<<<N_TOK, 256, 0, stream>>>(x, ids, gw, uw, dw, sgw, suw, sdw, out);
    return;
  }

  char* ws = (char*)d_ws;
  int* ctrl = (int*)ws;                                   // cnt[8] | cursor[8] | off[9]
  int* perm = (int*)(ws + 1024);                          // 33792 ints
  unsigned short* xbf = (unsigned short*)(ws + 262144);   // [32768][1024]
  unsigned short* Gt = (unsigned short*)(ws + 67371008ull);   // [8][1024][1024]
  unsigned short* Ut = (unsigned short*)(ws + 84148224ull);
  unsigned short* Dt = (unsigned short*)(ws + 100925440ull);
  unsigned short* inter = (unsigned short*)(ws + 117702656ull); // [33792][1024]

  k_zero<<<1, 64, 0, stream>>>(ctrl);
  k_count<<<128, 256, 0, stream>>>(ids, ctrl);
  k_scan<<<1, 64, 0, stream>>>(ctrl, ctrl + 16);
  k_fill<<<128, 256, 0, stream>>>(ids, ctrl + 8, ctrl + 16, perm);
  k_cvt_x<<<16384, 256, 0, stream>>>(x, xbf);
  // routed transposes: gate/up [1024][512] -> [512][1024]; down [512][1024] -> [1024][512]
  k_transpose_cvt<<<dim3(16, 32, 8), 256, 0, stream>>>(gw, Gt, 1024, 512, 1024,
                                                       (size_t)1024 * 512, (size_t)1 << 20);
  k_transpose_cvt<<<dim3(16, 32, 8), 256, 0, stream>>>(uw, Ut, 1024, 512, 1024,
                                                       (size_t)1024 * 512, (size_t)1 << 20);
  k_transpose_cvt<<<dim3(32, 16, 8), 256, 0, stream>>>(dw, Dt, 512, 1024, 1024,
                                                       (size_t)512 * 1024, (size_t)1 << 20);
  // shared weights appended (replicated per expert)
  k_copy_cvt<<<dim3(512, 1, 8), 256, 0, stream>>>(sgw, Gt, 512, 1024, 1024, 512, 0, (size_t)1 << 20);
  k_copy_cvt<<<dim3(512, 1, 8), 256, 0, stream>>>(suw, Ut, 512, 1024, 1024, 512, 0, (size_t)1 << 20);
  k_copy_cvt<<<dim3(512, 1, 8), 256, 0, stream>>>(sdw, Dt, 1024, 512, 1024, 0, 512, (size_t)1 << 20);
  // grouped GEMMs
  k_gu<<<dim3(8, 256, 8), 256, 0, stream>>>(xbf, Gt, Ut, perm, ctrl, ctrl + 16, inter);
  k_down<<<dim3(4, 256, 8), 256, 0, stream>>>(inter, Dt, perm, ctrl, ctrl + 16, out);
}

// Round 5
// 495.659 us; speedup vs baseline: 1.5838x; 1.3071x over previous
//
#include <hip/hip_runtime.h>
#include <hip/hip_bf16.h>

// TokenRoutedMLP: N=32768 tokens, H=1024, 8 routed experts (id%8) + shared expert.
// Grouped bf16 MFMA GEMMs; shared expert folded via concat weights; gate/up
// interleaved by 16 cols in W1 so silu pairing is in-register (no shuffles).
//   inter[m, 0:512]   = silu(x@gate_e)*(x@up_e)     (routed)
//   inter[m, 512:1024]= silu(x@sgW^T)*(x@suW^T)     (shared)
//   out[tok] = inter @ [down_e ; sdW^T]             (K=1024)
// GEMMs: 256x256 tile, BK=64, 8 waves, double-buffered LDS with
// stage(t+1) -> compute(t) -> syncthreads (drain AFTER compute, m248 2ph pattern).
// global_load_lds LDS pointer MUST be wave-uniform (HW adds lane*16B) — m104/m108.

#define N_TOK 32768
#define HD 1024
#define NE 8

typedef __attribute__((ext_vector_type(8))) short bf16x8;
typedef __attribute__((ext_vector_type(8))) unsigned short u16x8;
typedef __attribute__((ext_vector_type(4))) float f32x4;

__device__ __forceinline__ unsigned short f2bf(float f) {
  unsigned int x = __float_as_uint(f);
  x += 0x7fffu + ((x >> 16) & 1u);   // RTNE
  return (unsigned short)(x >> 16);
}

__device__ __forceinline__ void gld16(const unsigned short* g, unsigned short* l) {
  __builtin_amdgcn_global_load_lds(
      (const __attribute__((address_space(1))) unsigned int*)g,
      (__attribute__((address_space(3))) unsigned int*)l,
      16, 0, 0);
}

__device__ __forceinline__ int expert_of(int id) {
  int v = id < 0 ? 0 : (id > 99999 ? 99999 : id);
  return v & 7;
}

// ---------------- routing (LDS-histogram; 8 global atomics per block) ----------
__global__ void k_zero(int* ctrl) {
  if (threadIdx.x < 16) ctrl[threadIdx.x] = 0;   // cnt[8], cursor[8]
}

__global__ void k_count(const int* __restrict__ ids, int* __restrict__ cnt) {
  __shared__ int l[NE];
  if (threadIdx.x < NE) l[threadIdx.x] = 0;
  __syncthreads();
  int t = blockIdx.x * 256 + threadIdx.x;
  atomicAdd(&l[expert_of(ids[t])], 1);
  __syncthreads();
  if (threadIdx.x < NE) atomicAdd(&cnt[threadIdx.x], l[threadIdx.x]);
}

__global__ void k_scan(const int* __restrict__ cnt, int* __restrict__ off) {
  if (threadIdx.x == 0 && blockIdx.x == 0) {
    int a = 0;
    for (int e = 0; e < NE; e++) { off[e] = a; a += (cnt[e] + 127) & ~127; }
    off[NE] = a;
  }
}

__global__ void k_fill(const int* __restrict__ ids, int* __restrict__ cursor,
                       const int* __restrict__ off, int* __restrict__ perm) {
  __shared__ int lcnt[NE], lbase[NE];
  if (threadIdx.x < NE) lcnt[threadIdx.x] = 0;
  __syncthreads();
  int t = blockIdx.x * 256 + threadIdx.x;
  int e = expert_of(ids[t]);
  int r = atomicAdd(&lcnt[e], 1);          // rank within block
  __syncthreads();
  if (threadIdx.x < NE)
    lbase[threadIdx.x] = atomicAdd(&cursor[threadIdx.x], lcnt[threadIdx.x]);
  __syncthreads();
  perm[off[e] + lbase[e] + r] = t;
}

// ---------------- conversions / weight build ----------------
__global__ void k_cvt_x(const float* __restrict__ src, unsigned short* __restrict__ dst) {
  size_t i = ((size_t)blockIdx.x * 256 + threadIdx.x) * 8;
  float4 a = *reinterpret_cast<const float4*>(src + i);
  float4 b = *reinterpret_cast<const float4*>(src + i + 4);
  u16x8 o;
  o[0]=f2bf(a.x); o[1]=f2bf(a.y); o[2]=f2bf(a.z); o[3]=f2bf(a.w);
  o[4]=f2bf(b.x); o[5]=f2bf(b.y); o[6]=f2bf(b.z); o[7]=f2bf(b.w);
  *reinterpret_cast<u16x8*>(dst + i) = o;
}

// row remap: mode 0 plain; mode 1 gate-interleave; mode 2 up-interleave
__device__ __forceinline__ int rowmap(int c, int mode) {
  if (mode == 0) return c;
  return ((c >> 4) << 5) + (c & 15) + (mode == 2 ? 16 : 0);
}

// transpose-convert: src f32 [R][C] per expert -> dst bf16 [rowmap(col)][src_row], stride HD
__global__ void k_transpose_cvt(const float* __restrict__ src0, unsigned short* __restrict__ dst0,
                                int C, int mode, size_t src_estride, size_t dst_estride) {
  const float* src = src0 + blockIdx.z * src_estride;
  unsigned short* dst = dst0 + blockIdx.z * dst_estride;
  __shared__ __attribute__((aligned(16))) float tile[32][33];
  int t = threadIdx.x;
  int r0 = blockIdx.y * 32, c0 = blockIdx.x * 32;
  int row = t >> 3, c4 = (t & 7) * 4;
  float4 v = *reinterpret_cast<const float4*>(src + (size_t)(r0 + row) * C + c0 + c4);
  tile[row][c4+0] = v.x; tile[row][c4+1] = v.y; tile[row][c4+2] = v.z; tile[row][c4+3] = v.w;
  __syncthreads();
  ushort4 o;
  o.x = f2bf(tile[c4+0][row]); o.y = f2bf(tile[c4+1][row]);
  o.z = f2bf(tile[c4+2][row]); o.w = f2bf(tile[c4+3][row]);
  int orow = rowmap(c0 + row, mode);
  *reinterpret_cast<ushort4*>(dst + (size_t)orow * HD + r0 + c4) = o;
}

// copy-convert: src f32 [rows][cols] -> dst row (1024+rowmap(r) if mode, else r), col dcol+c
__global__ void k_copy_cvt(const float* __restrict__ src, unsigned short* __restrict__ dst,
                           int cols, int mode, int dcol, size_t dst_estride) {
  size_t i = ((size_t)blockIdx.x * 256 + threadIdx.x) * 4;
  int r = (int)(i / cols), c = (int)(i % cols);
  int row = (mode == 0) ? r : (1024 + rowmap(r, mode));
  float4 v = *reinterpret_cast<const float4*>(src + i);
  ushort4 o; o.x=f2bf(v.x); o.y=f2bf(v.y); o.z=f2bf(v.z); o.w=f2bf(v.w);
  *reinterpret_cast<ushort4*>(dst + blockIdx.z * dst_estride
                              + (size_t)row * HD + dcol + c) = o;
}

// ---------------- GEMM 1: x @ W1(interleaved gate/up) + silu*mul -> inter ----------
// 512 thr = 8 waves (2M x 4N). Tile M=256 tokens, N=256 W1-rows (=128 inter cols), BK=64.
__global__ __launch_bounds__(512, 2) void k_gu(
    const unsigned short* __restrict__ xbf,
    const unsigned short* __restrict__ W1,   // [8][2048][1024]
    const int* __restrict__ perm, const int* __restrict__ cnt, const int* __restrict__ off,
    unsigned short* __restrict__ inter) {
  const int e = blockIdx.z;
  const int ce = cnt[e];
  const int m0 = blockIdx.y * 256;
  if (m0 >= ce) return;
  const int cep = (ce + 127) & ~127;
  const int n0 = blockIdx.x * 256;
  const int oe = off[e];
  __shared__ __attribute__((aligned(16))) unsigned short smA[2 * 256 * 64];  // 64 KB
  __shared__ __attribute__((aligned(16))) unsigned short smB[2 * 256 * 64];  // 64 KB
  const int tid = threadIdx.x;
  const int lane = tid & 63;
  const int wv = tid >> 6;
  const int wm = wv >> 2, wn = wv & 3;

  // staging: thread t sources row (s*64 + t/8), k block (t%8)*8; LDS dest is
  // wave-uniform base + lane*16B (HW rule) == tid*16B within the slice.
  const int srow = tid >> 3;
  const int skol = (tid & 7) * 8;
  const unsigned short* sa[4];
  const unsigned short* sb[4];
#pragma unroll
  for (int s = 0; s < 4; s++) {
    int i = m0 + s * 64 + srow;
    if (i > ce - 1) i = ce - 1;
    int tok = perm[oe + i];
    sa[s] = xbf + (size_t)tok * HD + skol;
    sb[s] = W1 + ((size_t)e << 21) + (size_t)(n0 + s * 64 + srow) * HD + skol;
  }

  f32x4 acc[8][4];
#pragma unroll
  for (int mi = 0; mi < 8; mi++)
#pragma unroll
    for (int ni = 0; ni < 4; ni++) acc[mi][ni] = (f32x4){0.f, 0.f, 0.f, 0.f};

  auto STAGE = [&](int b, int kt) {
    const int ko = kt * 64;
    unsigned short* la = smA + b * 16384 + wv * 512;   // wave-uniform
    unsigned short* lb = smB + b * 16384 + wv * 512;
#pragma unroll
    for (int s = 0; s < 4; s++) {
      gld16(sa[s] + ko, la + s * 4096);
      gld16(sb[s] + ko, lb + s * 4096);
    }
  };
  auto COMPUTE = [&](int b) {
    const unsigned short* A = smA + b * 16384;
    const unsigned short* B = smB + b * 16384;
#pragma unroll
    for (int ks = 0; ks < 2; ks++) {
      bf16x8 a[8], bb[4];
#pragma unroll
      for (int mi = 0; mi < 8; mi++)
        a[mi] = *reinterpret_cast<const bf16x8*>(A + (wm * 128 + mi * 16 + (lane & 15)) * 64 + ks * 32 + (lane >> 4) * 8);
#pragma unroll
      for (int ni = 0; ni < 4; ni++)
        bb[ni] = *reinterpret_cast<const bf16x8*>(B + (wn * 64 + ni * 16 + (lane & 15)) * 64 + ks * 32 + (lane >> 4) * 8);
#pragma unroll
      for (int mi = 0; mi < 8; mi++)
#pragma unroll
        for (int ni = 0; ni < 4; ni++)
          acc[mi][ni] = __builtin_amdgcn_mfma_f32_16x16x32_bf16(a[mi], bb[ni], acc[mi][ni], 0, 0, 0);
    }
  };

  STAGE(0, 0);
  __syncthreads();
  int cur = 0;
#pragma unroll 1
  for (int kt = 0; kt < 15; kt++) {
    STAGE(cur ^ 1, kt + 1);   // prefetch next tile (in flight during MFMA)
    COMPUTE(cur);
    __syncthreads();          // drains vmcnt(0): next buffer ready; cur buffer free
    cur ^= 1;
  }
  COMPUTE(cur);

  // epilogue: n-frags alternate (gate, up) per 16; pair in-register
  const int colbase = (n0 + wn * 64) >> 1;
#pragma unroll
  for (int mi = 0; mi < 8; mi++)
#pragma unroll
    for (int p = 0; p < 2; p++)
#pragma unroll
      for (int r = 0; r < 4; r++) {
        int m = wm * 128 + mi * 16 + (lane >> 4) * 4 + r;
        if (m0 + m < cep) {
          float g = acc[mi][2 * p][r];
          float u = acc[mi][2 * p + 1][r];
          float sv = g / (1.f + __expf(-g)) * u;
          inter[(size_t)(oe + m0 + m) * HD + colbase + p * 16 + (lane & 15)] = f2bf(sv);
        }
      }
}

// ---------------- GEMM 2: inter @ Dcat -> out (scatter rows via perm) ----------------
// Same skeleton. Tile M=256, N=256 out cols, BK=64.
__global__ __launch_bounds__(512, 2) void k_down(
    const unsigned short* __restrict__ inter,
    const unsigned short* __restrict__ Dt,   // [8][1024][1024] B^T
    const int* __restrict__ perm, const int* __restrict__ cnt, const int* __restrict__ off,
    float* __restrict__ out) {
  const int e = blockIdx.z;
  const int ce = cnt[e];
  const int m0 = blockIdx.y * 256;
  if (m0 >= ce) return;
  const int cep = (ce + 127) & ~127;
  const int n0 = blockIdx.x * 256;
  const int oe = off[e];
  __shared__ __attribute__((aligned(16))) unsigned short smA[2 * 256 * 64];
  __shared__ __attribute__((aligned(16))) unsigned short smB[2 * 256 * 64];
  const int tid = threadIdx.x;
  const int lane = tid & 63;
  const int wv = tid >> 6;
  const int wm = wv >> 2, wn = wv & 3;

  const int srow = tid >> 3;
  const int skol = (tid & 7) * 8;
  const unsigned short* sa[4];
  const unsigned short* sb[4];
#pragma unroll
  for (int s = 0; s < 4; s++) {
    int i = m0 + s * 64 + srow;
    if (i > cep - 1) i = cep - 1;     // inter rows [0, cep) are valid
    sa[s] = inter + (size_t)(oe + i) * HD + skol;
    sb[s] = Dt + ((size_t)e << 20) + (size_t)(n0 + s * 64 + srow) * HD + skol;
  }

  f32x4 acc[8][4];
#pragma unroll
  for (int mi = 0; mi < 8; mi++)
#pragma unroll
    for (int ni = 0; ni < 4; ni++) acc[mi][ni] = (f32x4){0.f, 0.f, 0.f, 0.f};

  auto STAGE = [&](int b, int kt) {
    const int ko = kt * 64;
    unsigned short* la = smA + b * 16384 + wv * 512;   // wave-uniform
    unsigned short* lb = smB + b * 16384 + wv * 512;
#pragma unroll
    for (int s = 0; s < 4; s++) {
      gld16(sa[s] + ko, la + s * 4096);
      gld16(sb[s] + ko, lb + s * 4096);
    }
  };
  auto COMPUTE = [&](int b) {
    const unsigned short* A = smA + b * 16384;
    const unsigned short* B = smB + b * 16384;
#pragma unroll
    for (int ks = 0; ks < 2; ks++) {
      bf16x8 a[8], bb[4];
#pragma unroll
      for (int mi = 0; mi < 8; mi++)
        a[mi] = *reinterpret_cast<const bf16x8*>(A + (wm * 128 + mi * 16 + (lane & 15)) * 64 + ks * 32 + (lane >> 4) * 8);
#pragma unroll
      for (int ni = 0; ni < 4; ni++)
        bb[ni] = *reinterpret_cast<const bf16x8*>(B + (wn * 64 + ni * 16 + (lane & 15)) * 64 + ks * 32 + (lane >> 4) * 8);
#pragma unroll
      for (int mi = 0; mi < 8; mi++)
#pragma unroll
        for (int ni = 0; ni < 4; ni++)
          acc[mi][ni] = __builtin_amdgcn_mfma_f32_16x16x32_bf16(a[mi], bb[ni], acc[mi][ni], 0, 0, 0);
    }
  };

  STAGE(0, 0);
  __syncthreads();
  int cur = 0;
#pragma unroll 1
  for (int kt = 0; kt < 15; kt++) {
    STAGE(cur ^ 1, kt + 1);
    COMPUTE(cur);
    __syncthreads();
    cur ^= 1;
  }
  COMPUTE(cur);

#pragma unroll
  for (int mi = 0; mi < 8; mi++)
#pragma unroll
    for (int r = 0; r < 4; r++) {
      int m = wm * 128 + mi * 16 + (lane >> 4) * 4 + r;
      int gm = m0 + m;
      if (gm < ce) {
        int t = perm[oe + gm];
#pragma unroll
        for (int ni = 0; ni < 4; ni++)
          out[(size_t)t * HD + n0 + wn * 64 + ni * 16 + (lane & 15)] = acc[mi][ni][r];
      }
    }
}

// ---------------- naive fp32 fallback (only if ws too small) ----------------
__global__ __launch_bounds__(256) void k_naive(
    const float* __restrict__ x, const int* __restrict__ ids,
    const float* __restrict__ gw, const float* __restrict__ uw, const float* __restrict__ dw,
    const float* __restrict__ sgw, const float* __restrict__ suw, const float* __restrict__ sdw,
    float* __restrict__ out) {
  const int t = blockIdx.x;
  const int tid = threadIdx.x;
  __shared__ float sx[1024];
  __shared__ float si[1024];
  for (int i = tid; i < 1024; i += 256) sx[i] = x[(size_t)t * 1024 + i];
  const int e = expert_of(ids[t]);
  __syncthreads();
  const float* gwe = gw + (size_t)e * 1024 * 512;
  const float* uwe = uw + (size_t)e * 1024 * 512;
  for (int j = tid; j < 512; j += 256) {
    float g = 0, u = 0, sg = 0, su = 0;
    for (int k = 0; k < 1024; k++) {
      float xv = sx[k];
      g += xv * gwe[(size_t)k * 512 + j];
      u += xv * uwe[(size_t)k * 512 + j];
      sg += xv * sgw[(size_t)j * 1024 + k];
      su += xv * suw[(size_t)j * 1024 + k];
    }
    si[j] = g / (1.f + __expf(-g)) * u;
    si[512 + j] = sg / (1.f + __expf(-sg)) * su;
  }
  __syncthreads();
  const float* dwe = dw + (size_t)e * 512 * 1024;
  for (int n = tid; n < 1024; n += 256) {
    float a = 0;
    for (int k = 0; k < 512; k++)
      a += si[k] * dwe[(size_t)k * 1024 + n] + si[512 + k] * sdw[(size_t)n * 512 + k];
    out[(size_t)t * 1024 + n] = a;
  }
}

extern "C" void kernel_launch(void* const* d_in, const int* in_sizes, int n_in,
                              void* d_out, int out_size, void* d_ws, size_t ws_size,
                              hipStream_t stream) {
  const float* x = (const float*)d_in[0];
  const int* ids = (const int*)d_in[1];          // harness passes integers as int32
  const float* gw = (const float*)d_in[2];
  const float* uw = (const float*)d_in[3];
  const float* dw = (const float*)d_in[4];
  const float* sgw = (const float*)d_in[5];
  const float* suw = (const float*)d_in[6];
  const float* sdw = (const float*)d_in[7];
  float* out = (float*)d_out;

  const size_t REQ = 186908672ull;
  if (ws_size < REQ) {
    k_naive<<<N_TOK, 256, 0, stream>>>(x, ids, gw, uw, dw, sgw, suw, sdw, out);
    return;
  }

  char* ws = (char*)d_ws;
  int* ctrl = (int*)ws;                                   // cnt[8] | cursor[8] | off[9]
  int* perm = (int*)(ws + 1024);                          // 33792 ints
  unsigned short* xbf = (unsigned short*)(ws + 262144);   // [32768][1024]
  unsigned short* W1 = (unsigned short*)(ws + 67371008ull);   // [8][2048][1024] interleaved
  unsigned short* Dt = (unsigned short*)(ws + 100925440ull);  // [8][1024][1024]
  unsigned short* inter = (unsigned short*)(ws + 117702656ull); // [33792][1024]

  k_zero<<<1, 64, 0, stream>>>(ctrl);
  k_count<<<128, 256, 0, stream>>>(ids, ctrl);
  k_scan<<<1, 64, 0, stream>>>(ctrl, ctrl + 16);
  k_fill<<<128, 256, 0, stream>>>(ids, ctrl + 8, ctrl + 16, perm);
  k_cvt_x<<<16384, 256, 0, stream>>>(x, xbf);
  // routed weights: gate/up [1024][512] -> W1 interleaved rows; down [512][1024] -> Dt plain
  k_transpose_cvt<<<dim3(16, 32, 8), 256, 0, stream>>>(gw, W1, 512, 1,
                                                       (size_t)1024 * 512, (size_t)1 << 21);
  k_transpose_cvt<<<dim3(16, 32, 8), 256, 0, stream>>>(uw, W1, 512, 2,
                                                       (size_t)1024 * 512, (size_t)1 << 21);
  k_transpose_cvt<<<dim3(32, 16, 8), 256, 0, stream>>>(dw, Dt, 1024, 0,
                                                       (size_t)512 * 1024, (size_t)1 << 20);
  // shared weights appended (replicated per expert)
  k_copy_cvt<<<dim3(512, 1, 8), 256, 0, stream>>>(sgw, W1, 1024, 1, 0, (size_t)1 << 21);
  k_copy_cvt<<<dim3(512, 1, 8), 256, 0, stream>>>(suw, W1, 1024, 2, 0, (size_t)1 << 21);
  k_copy_cvt<<<dim3(512, 1, 8), 256, 0, stream>>>(sdw, Dt, 512, 0, 512, (size_t)1 << 20);
  // grouped GEMMs
  k_gu<<<dim3(8, 128, 8), 512, 0, stream>>>(xbf, W1, perm, ctrl, ctrl + 16, inter);
  k_down<<<dim3(4, 128, 8), 512, 0, stream>>>(inter, Dt, perm, ctrl, ctrl + 16, out);
}

// Round 6
// 376.707 us; speedup vs baseline: 2.0839x; 1.3158x over previous
//
#include <hip/hip_runtime.h>
#include <hip/hip_bf16.h>

// TokenRoutedMLP: N=32768 tokens, H=1024, 8 routed experts (id%8) + shared expert.
// Grouped bf16 MFMA GEMMs; shared expert folded via concat weights; gate/up
// interleaved by 16 cols in W1 so silu pairing is in-register.
// GEMMs: m97-class structure — 128x128 tile, BK=32, 4 waves, 32 KiB LDS,
// dbuf-prefetch 2ph (STAGE(t+1) || COMPUTE(t) -> syncthreads), ~3 blocks/CU
// so the vmcnt(0) drain at the barrier is hidden by other resident blocks.
// global_load_lds LDS pointer MUST be wave-uniform (HW adds lane*16B) — m104/m108.

#define N_TOK 32768
#define HD 1024
#define NE 8

typedef __attribute__((ext_vector_type(8))) short bf16x8;
typedef __attribute__((ext_vector_type(8))) unsigned short u16x8;
typedef __attribute__((ext_vector_type(4))) float f32x4;

__device__ __forceinline__ unsigned short f2bf(float f) {
  unsigned int x = __float_as_uint(f);
  x += 0x7fffu + ((x >> 16) & 1u);   // RTNE
  return (unsigned short)(x >> 16);
}

__device__ __forceinline__ void gld16(const unsigned short* g, unsigned short* l) {
  __builtin_amdgcn_global_load_lds(
      (const __attribute__((address_space(1))) unsigned int*)g,
      (__attribute__((address_space(3))) unsigned int*)l,
      16, 0, 0);
}

__device__ __forceinline__ int expert_of(int id) {
  int v = id < 0 ? 0 : (id > 99999 ? 99999 : id);
  return v & 7;
}

// ---------------- routing (LDS-histogram; 8 global atomics per block) ----------
__global__ void k_zero(int* ctrl) {
  if (threadIdx.x < 16) ctrl[threadIdx.x] = 0;   // cnt[8], cursor[8]
}

__global__ void k_count(const int* __restrict__ ids, int* __restrict__ cnt) {
  __shared__ int l[NE];
  if (threadIdx.x < NE) l[threadIdx.x] = 0;
  __syncthreads();
  int t = blockIdx.x * 256 + threadIdx.x;
  atomicAdd(&l[expert_of(ids[t])], 1);
  __syncthreads();
  if (threadIdx.x < NE) atomicAdd(&cnt[threadIdx.x], l[threadIdx.x]);
}

__global__ void k_scan(const int* __restrict__ cnt, int* __restrict__ off) {
  if (threadIdx.x == 0 && blockIdx.x == 0) {
    int a = 0;
    for (int e = 0; e < NE; e++) { off[e] = a; a += (cnt[e] + 127) & ~127; }
    off[NE] = a;
  }
}

__global__ void k_fill(const int* __restrict__ ids, int* __restrict__ cursor,
                       const int* __restrict__ off, int* __restrict__ perm) {
  __shared__ int lcnt[NE], lbase[NE];
  if (threadIdx.x < NE) lcnt[threadIdx.x] = 0;
  __syncthreads();
  int t = blockIdx.x * 256 + threadIdx.x;
  int e = expert_of(ids[t]);
  int r = atomicAdd(&lcnt[e], 1);          // rank within block
  __syncthreads();
  if (threadIdx.x < NE)
    lbase[threadIdx.x] = atomicAdd(&cursor[threadIdx.x], lcnt[threadIdx.x]);
  __syncthreads();
  perm[off[e] + lbase[e] + r] = t;
}

// ---------------- conversions / weight build ----------------
__global__ void k_cvt_x(const float* __restrict__ src, unsigned short* __restrict__ dst) {
  size_t i = ((size_t)blockIdx.x * 256 + threadIdx.x) * 8;
  float4 a = *reinterpret_cast<const float4*>(src + i);
  float4 b = *reinterpret_cast<const float4*>(src + i + 4);
  u16x8 o;
  o[0]=f2bf(a.x); o[1]=f2bf(a.y); o[2]=f2bf(a.z); o[3]=f2bf(a.w);
  o[4]=f2bf(b.x); o[5]=f2bf(b.y); o[6]=f2bf(b.z); o[7]=f2bf(b.w);
  *reinterpret_cast<u16x8*>(dst + i) = o;
}

// row remap: mode 0 plain; mode 1 gate-interleave; mode 2 up-interleave
__device__ __forceinline__ int rowmap(int c, int mode) {
  if (mode == 0) return c;
  return ((c >> 4) << 5) + (c & 15) + (mode == 2 ? 16 : 0);
}

// transpose-convert: src f32 [R][C] per expert -> dst bf16 [rowmap(col)][src_row], stride HD
__global__ void k_transpose_cvt(const float* __restrict__ src0, unsigned short* __restrict__ dst0,
                                int C, int mode, size_t src_estride, size_t dst_estride) {
  const float* src = src0 + blockIdx.z * src_estride;
  unsigned short* dst = dst0 + blockIdx.z * dst_estride;
  __shared__ __attribute__((aligned(16))) float tile[32][33];
  int t = threadIdx.x;
  int r0 = blockIdx.y * 32, c0 = blockIdx.x * 32;
  int row = t >> 3, c4 = (t & 7) * 4;
  float4 v = *reinterpret_cast<const float4*>(src + (size_t)(r0 + row) * C + c0 + c4);
  tile[row][c4+0] = v.x; tile[row][c4+1] = v.y; tile[row][c4+2] = v.z; tile[row][c4+3] = v.w;
  __syncthreads();
  ushort4 o;
  o.x = f2bf(tile[c4+0][row]); o.y = f2bf(tile[c4+1][row]);
  o.z = f2bf(tile[c4+2][row]); o.w = f2bf(tile[c4+3][row]);
  int orow = rowmap(c0 + row, mode);
  *reinterpret_cast<ushort4*>(dst + (size_t)orow * HD + r0 + c4) = o;
}

// copy-convert: src f32 [rows][cols] -> dst row (1024+rowmap(r) if mode, else r), col dcol+c
__global__ void k_copy_cvt(const float* __restrict__ src, unsigned short* __restrict__ dst,
                           int cols, int mode, int dcol, size_t dst_estride) {
  size_t i = ((size_t)blockIdx.x * 256 + threadIdx.x) * 4;
  int r = (int)(i / cols), c = (int)(i % cols);
  int row = (mode == 0) ? r : (1024 + rowmap(r, mode));
  float4 v = *reinterpret_cast<const float4*>(src + i);
  ushort4 o; o.x=f2bf(v.x); o.y=f2bf(v.y); o.z=f2bf(v.z); o.w=f2bf(v.w);
  *reinterpret_cast<ushort4*>(dst + blockIdx.z * dst_estride
                              + (size_t)row * HD + dcol + c) = o;
}

// ---------------- GEMM 1: x @ W1(interleaved gate/up) + silu*mul -> inter ----------
// 256 thr = 4 waves (2x2). Tile M=128 tokens, N=128 W1-rows (=64 inter cols), BK=32.
// Per wave-K-step: 16 MFMA, 8 ds_read_b128, 4 gld16 (m97 histogram).
__global__ __launch_bounds__(256, 3) void k_gu(
    const unsigned short* __restrict__ xbf,
    const unsigned short* __restrict__ W1,   // [8][2048][1024]
    const int* __restrict__ perm, const int* __restrict__ cnt, const int* __restrict__ off,
    unsigned short* __restrict__ inter) {
  const int e = blockIdx.z;
  const int ce = cnt[e];
  const int m0 = blockIdx.y * 128;
  if (m0 >= ce) return;
  const int n0 = blockIdx.x * 128;
  const int oe = off[e];
  __shared__ __attribute__((aligned(16))) unsigned short smA[2 * 128 * 32];  // 16 KB
  __shared__ __attribute__((aligned(16))) unsigned short smB[2 * 128 * 32];  // 16 KB
  const int tid = threadIdx.x;
  const int lane = tid & 63;
  const int wv = tid >> 6;
  const int wm = wv >> 1, wn = wv & 1;

  // staging: thread t covers row (s*64 + t/4), k-col (t%4)*8 (16B)
  const int srow = tid >> 2;
  const int skol = (tid & 3) * 8;
  const unsigned short* sa[2];
  const unsigned short* sb[2];
#pragma unroll
  for (int s = 0; s < 2; s++) {
    int i = m0 + s * 64 + srow;
    if (i > ce - 1) i = ce - 1;
    int tok = perm[oe + i];
    sa[s] = xbf + (size_t)tok * HD + skol;
    sb[s] = W1 + ((size_t)e << 21) + (size_t)(n0 + s * 64 + srow) * HD + skol;
  }

  f32x4 acc[4][4];
#pragma unroll
  for (int mi = 0; mi < 4; mi++)
#pragma unroll
    for (int ni = 0; ni < 4; ni++) acc[mi][ni] = (f32x4){0.f, 0.f, 0.f, 0.f};

  auto STAGE = [&](int b, int kt) {
    const int ko = kt * 32;
#pragma unroll
    for (int s = 0; s < 2; s++) {
      gld16(sa[s] + ko, smA + b * 4096 + s * 2048 + wv * 512);  // wave-uniform dest
      gld16(sb[s] + ko, smB + b * 4096 + s * 2048 + wv * 512);
    }
  };
  auto COMPUTE = [&](int b) {
    const unsigned short* A = smA + b * 4096;
    const unsigned short* B = smB + b * 4096;
    bf16x8 a[4], bb[4];
#pragma unroll
    for (int mi = 0; mi < 4; mi++)
      a[mi] = *reinterpret_cast<const bf16x8*>(A + (wm * 64 + mi * 16 + (lane & 15)) * 32 + (lane >> 4) * 8);
#pragma unroll
    for (int ni = 0; ni < 4; ni++)
      bb[ni] = *reinterpret_cast<const bf16x8*>(B + (wn * 64 + ni * 16 + (lane & 15)) * 32 + (lane >> 4) * 8);
#pragma unroll
    for (int mi = 0; mi < 4; mi++)
#pragma unroll
      for (int ni = 0; ni < 4; ni++)
        acc[mi][ni] = __builtin_amdgcn_mfma_f32_16x16x32_bf16(a[mi], bb[ni], acc[mi][ni], 0, 0, 0);
  };

  STAGE(0, 0);
  __syncthreads();
  int cur = 0;
#pragma unroll 1
  for (int kt = 0; kt < 31; kt++) {
    STAGE(cur ^ 1, kt + 1);   // next tile's loads fly during this tile's MFMA
    COMPUTE(cur);
    __syncthreads();          // drains vmcnt(0); other resident blocks hide it
    cur ^= 1;
  }
  COMPUTE(cur);

  // epilogue: n-frags alternate (gate, up) per 16; pair in-register.
  // active tile => all 128 rows < cep (cep 128-aligned), no row guard needed.
  const int colbase = (n0 + wn * 64) >> 1;
#pragma unroll
  for (int mi = 0; mi < 4; mi++)
#pragma unroll
    for (int p = 0; p < 2; p++)
#pragma unroll
      for (int r = 0; r < 4; r++) {
        int m = wm * 64 + mi * 16 + (lane >> 4) * 4 + r;
        float g = acc[mi][2 * p][r];
        float u = acc[mi][2 * p + 1][r];
        float sv = g / (1.f + __expf(-g)) * u;
        inter[(size_t)(oe + m0 + m) * HD + colbase + p * 16 + (lane & 15)] = f2bf(sv);
      }
}

// ---------------- GEMM 2: inter @ Dcat -> out (scatter rows via perm) ----------------
// Same skeleton. Tile M=128, N=128 out cols, BK=32.
__global__ __launch_bounds__(256, 3) void k_down(
    const unsigned short* __restrict__ inter,
    const unsigned short* __restrict__ Dt,   // [8][1024][1024] B^T
    const int* __restrict__ perm, const int* __restrict__ cnt, const int* __restrict__ off,
    float* __restrict__ out) {
  const int e = blockIdx.z;
  const int ce = cnt[e];
  const int m0 = blockIdx.y * 128;
  if (m0 >= ce) return;
  const int n0 = blockIdx.x * 128;
  const int oe = off[e];
  __shared__ __attribute__((aligned(16))) unsigned short smA[2 * 128 * 32];
  __shared__ __attribute__((aligned(16))) unsigned short smB[2 * 128 * 32];
  const int tid = threadIdx.x;
  const int lane = tid & 63;
  const int wv = tid >> 6;
  const int wm = wv >> 1, wn = wv & 1;

  const int srow = tid >> 2;
  const int skol = (tid & 3) * 8;
  const unsigned short* sa[2];
  const unsigned short* sb[2];
#pragma unroll
  for (int s = 0; s < 2; s++) {
    sa[s] = inter + (size_t)(oe + m0 + s * 64 + srow) * HD + skol;  // rows < cep valid
    sb[s] = Dt + ((size_t)e << 20) + (size_t)(n0 + s * 64 + srow) * HD + skol;
  }

  f32x4 acc[4][4];
#pragma unroll
  for (int mi = 0; mi < 4; mi++)
#pragma unroll
    for (int ni = 0; ni < 4; ni++) acc[mi][ni] = (f32x4){0.f, 0.f, 0.f, 0.f};

  auto STAGE = [&](int b, int kt) {
    const int ko = kt * 32;
#pragma unroll
    for (int s = 0; s < 2; s++) {
      gld16(sa[s] + ko, smA + b * 4096 + s * 2048 + wv * 512);
      gld16(sb[s] + ko, smB + b * 4096 + s * 2048 + wv * 512);
    }
  };
  auto COMPUTE = [&](int b) {
    const unsigned short* A = smA + b * 4096;
    const unsigned short* B = smB + b * 4096;
    bf16x8 a[4], bb[4];
#pragma unroll
    for (int mi = 0; mi < 4; mi++)
      a[mi] = *reinterpret_cast<const bf16x8*>(A + (wm * 64 + mi * 16 + (lane & 15)) * 32 + (lane >> 4) * 8);
#pragma unroll
    for (int ni = 0; ni < 4; ni++)
      bb[ni] = *reinterpret_cast<const bf16x8*>(B + (wn * 64 + ni * 16 + (lane & 15)) * 32 + (lane >> 4) * 8);
#pragma unroll
    for (int mi = 0; mi < 4; mi++)
#pragma unroll
      for (int ni = 0; ni < 4; ni++)
        acc[mi][ni] = __builtin_amdgcn_mfma_f32_16x16x32_bf16(a[mi], bb[ni], acc[mi][ni], 0, 0, 0);
  };

  STAGE(0, 0);
  __syncthreads();
  int cur = 0;
#pragma unroll 1
  for (int kt = 0; kt < 31; kt++) {
    STAGE(cur ^ 1, kt + 1);
    COMPUTE(cur);
    __syncthreads();
    cur ^= 1;
  }
  COMPUTE(cur);

#pragma unroll
  for (int mi = 0; mi < 4; mi++)
#pragma unroll
    for (int r = 0; r < 4; r++) {
      int m = wm * 64 + mi * 16 + (lane >> 4) * 4 + r;
      int gm = m0 + m;
      if (gm < ce) {                      // only real tokens scatter
        int t = perm[oe + gm];
#pragma unroll
        for (int ni = 0; ni < 4; ni++)
          out[(size_t)t * HD + n0 + wn * 64 + ni * 16 + (lane & 15)] = acc[mi][ni][r];
      }
    }
}

// ---------------- naive fp32 fallback (only if ws too small) ----------------
__global__ __launch_bounds__(256) void k_naive(
    const float* __restrict__ x, const int* __restrict__ ids,
    const float* __restrict__ gw, const float* __restrict__ uw, const float* __restrict__ dw,
    const float* __restrict__ sgw, const float* __restrict__ suw, const float* __restrict__ sdw,
    float* __restrict__ out) {
  const int t = blockIdx.x;
  const int tid = threadIdx.x;
  __shared__ float sx[1024];
  __shared__ float si[1024];
  for (int i = tid; i < 1024; i += 256) sx[i] = x[(size_t)t * 1024 + i];
  const int e = expert_of(ids[t]);
  __syncthreads();
  const float* gwe = gw + (size_t)e * 1024 * 512;
  const float* uwe = uw + (size_t)e * 1024 * 512;
  for (int j = tid; j < 512; j += 256) {
    float g = 0, u = 0, sg = 0, su = 0;
    for (int k = 0; k < 1024; k++) {
      float xv = sx[k];
      g += xv * gwe[(size_t)k * 512 + j];
      u += xv * uwe[(size_t)k * 512 + j];
      sg += xv * sgw[(size_t)j * 1024 + k];
      su += xv * suw[(size_t)j * 1024 + k];
    }
    si[j] = g / (1.f + __expf(-g)) * u;
    si[512 + j] = sg / (1.f + __expf(-sg)) * su;
  }
  __syncthreads();
  const float* dwe = dw + (size_t)e * 512 * 1024;
  for (int n = tid; n < 1024; n += 256) {
    float a = 0;
    for (int k = 0; k < 512; k++)
      a += si[k] * dwe[(size_t)k * 1024 + n] + si[512 + k] * sdw[(size_t)n * 512 + k];
    out[(size_t)t * 1024 + n] = a;
  }
}

extern "C" void kernel_launch(void* const* d_in, const int* in_sizes, int n_in,
                              void* d_out, int out_size, void* d_ws, size_t ws_size,
                              hipStream_t stream) {
  const float* x = (const float*)d_in[0];
  const int* ids = (const int*)d_in[1];          // harness passes integers as int32
  const float* gw = (const float*)d_in[2];
  const float* uw = (const float*)d_in[3];
  const float* dw = (const float*)d_in[4];
  const float* sgw = (const float*)d_in[5];
  const float* suw = (const float*)d_in[6];
  const float* sdw = (const float*)d_in[7];
  float* out = (float*)d_out;

  const size_t REQ = 186908672ull;
  if (ws_size < REQ) {
    k_naive<<<N_TOK, 256, 0, stream>>>(x, ids, gw, uw, dw, sgw, suw, sdw, out);
    return;
  }

  char* ws = (char*)d_ws;
  int* ctrl = (int*)ws;                                   // cnt[8] | cursor[8] | off[9]
  int* perm = (int*)(ws + 1024);                          // 33792 ints
  unsigned short* xbf = (unsigned short*)(ws + 262144);   // [32768][1024]
  unsigned short* W1 = (unsigned short*)(ws + 67371008ull);   // [8][2048][1024] interleaved
  unsigned short* Dt = (unsigned short*)(ws + 100925440ull);  // [8][1024][1024]
  unsigned short* inter = (unsigned short*)(ws + 117702656ull); // [33792][1024]

  k_zero<<<1, 64, 0, stream>>>(ctrl);
  k_count<<<128, 256, 0, stream>>>(ids, ctrl);
  k_scan<<<1, 64, 0, stream>>>(ctrl, ctrl + 16);
  k_fill<<<128, 256, 0, stream>>>(ids, ctrl + 8, ctrl + 16, perm);
  k_cvt_x<<<16384, 256, 0, stream>>>(x, xbf);
  // routed weights: gate/up [1024][512] -> W1 interleaved rows; down [512][1024] -> Dt plain
  k_transpose_cvt<<<dim3(16, 32, 8), 256, 0, stream>>>(gw, W1, 512, 1,
                                                       (size_t)1024 * 512, (size_t)1 << 21);
  k_transpose_cvt<<<dim3(16, 32, 8), 256, 0, stream>>>(uw, W1, 512, 2,
                                                       (size_t)1024 * 512, (size_t)1 << 21);
  k_transpose_cvt<<<dim3(32, 16, 8), 256, 0, stream>>>(dw, Dt, 1024, 0,
                                                       (size_t)512 * 1024, (size_t)1 << 20);
  // shared weights appended (replicated per expert)
  k_copy_cvt<<<dim3(512, 1, 8), 256, 0, stream>>>(sgw, W1, 1024, 1, 0, (size_t)1 << 21);
  k_copy_cvt<<<dim3(512, 1, 8), 256, 0, stream>>>(suw, W1, 1024, 2, 0, (size_t)1 << 21);
  k_copy_cvt<<<dim3(512, 1, 8), 256, 0, stream>>>(sdw, Dt, 512, 0, 512, (size_t)1 << 20);
  // grouped GEMMs (128^2 tiles)
  k_gu<<<dim3(16, 256, 8), 256, 0, stream>>>(xbf, W1, perm, ctrl, ctrl + 16, inter);
  k_down<<<dim3(8, 256, 8), 256, 0, stream>>>(inter, Dt, perm, ctrl, ctrl + 16, out);
}